// Round 1
// baseline (80.226 us; speedup 1.0000x reference)
//
#include <hip/hip_runtime.h>

// Problem constants (from reference setup_inputs)
#define B_  4
#define H_  64
#define W_  64
#define C_  16
#define F_  32
#define WSTRIDE 32  // floats per (r,c,f) weight pack entry: [0..8]=t_rot, [9..17]=k_rot

// Packed rotated weights: pack[((r*16+c)*32+f)*32 + q]
__device__ float g_pack[4 * C_ * F_ * WSTRIDE];

// ---- prep: rotate + repack weights so each (r,c,f) slice is contiguous ----
__global__ void mtp_prep(const float* __restrict__ kern, const float* __restrict__ tker) {
    int idx = blockIdx.x * 256 + threadIdx.x;           // 0 .. 4*16*32-1
    if (idx >= 4 * C_ * F_) return;
    int f = idx & 31;
    int c = (idx >> 5) & 15;
    int r = idx >> 9;
    float* dst = g_pack + idx * WSTRIDE;
    #pragma unroll
    for (int ki = 0; ki < 3; ki++) {
        #pragma unroll
        for (int kj = 0; kj < 3; kj++) {
            int si, sj;
            switch (r) {                                // rot90^r (CCW), numpy semantics
                case 0:  si = ki;      sj = kj;      break;
                case 1:  si = kj;      sj = 2 - ki;  break;
                case 2:  si = 2 - ki;  sj = 2 - kj;  break;
                default: si = 2 - kj;  sj = ki;      break;
            }
            int p   = ki * 3 + kj;
            int src = ((si * 3 + sj) * C_ + c) * F_ + f;
            dst[p]     = tker[src];                     // times (slope)
            dst[9 + p] = kern[src];                     // plus (offset)
        }
    }
}

__device__ __forceinline__ float comp4(const float4& v, int c) {
    switch (c) { case 0: return v.x; case 1: return v.y; case 2: return v.z; default: return v.w; }
}

// ---- main: wave = one output row (64 pixels), computes 16 of 32 f's ----
// grid = 512 blocks x 256 threads (4 waves). Block -> (r, b, 2 rows x 2 f-halves).
__global__ __launch_bounds__(256) void mtp_main(const float* __restrict__ x,
                                                float* __restrict__ out) {
    const int lane = threadIdx.x & 63;
    // readfirstlane: make wave-id uniform for divergence analysis -> weight
    // addresses become uniform -> compiler can use the scalar (SMEM) pipe.
    const int wave = __builtin_amdgcn_readfirstlane(threadIdx.x >> 6);

    const int bid  = blockIdx.x;          // 0..511
    const int r    = bid >> 7;            // 0..3
    const int b    = (bid >> 5) & 3;      // 0..3
    const int igrp = bid & 31;            // 0..31
    const int i    = igrp * 2 + (wave >> 1);
    const int half = wave & 1;            // which 16 of the 32 f's
    const int j    = lane;                // pixel column

    float acc[16];
    #pragma unroll
    for (int ff = 0; ff < 16; ff++) acc[ff] = 0.0f;

    const float* wbase = g_pack + ((r * C_) * F_ + half * 16) * WSTRIDE;

    for (int cc = 0; cc < 4; cc++) {      // channel chunks of 4
        // Load 3x3 patch of float4 channel-chunks; OOB -> 0 (matches zero pad:
        // z = 0*t + k = k, exactly as the reference computes it).
        float4 xq[3][3];
        #pragma unroll
        for (int di = 0; di < 3; di++) {
            int row = i + di - 1;
            #pragma unroll
            for (int dj = 0; dj < 3; dj++) {
                int col = j + dj - 1;
                bool ok = (row >= 0) & (row < H_) & (col >= 0) & (col < W_);
                if (ok) {
                    xq[di][dj] = *reinterpret_cast<const float4*>(
                        x + (((b * H_ + row) * W_ + col) * C_ + cc * 4));
                } else {
                    xq[di][dj] = make_float4(0.f, 0.f, 0.f, 0.f);
                }
            }
        }
        #pragma unroll
        for (int c4 = 0; c4 < 4; c4++) {
            const int c = cc * 4 + c4;
            const float* wc = wbase + c * F_ * WSTRIDE;
            #pragma unroll
            for (int ff = 0; ff < 16; ff++) {
                const float* w = wc + ff * WSTRIDE;     // uniform address -> s_load
                float z[9];
                #pragma unroll
                for (int p = 0; p < 9; p++) {
                    float xv = comp4(xq[p / 3][p % 3], c4);
                    z[p] = fmaf(xv, w[p], w[9 + p]);
                }
                // 9-way max as nested fmax (clang fuses to v_max3_f32)
                float m1 = fmaxf(fmaxf(z[0], z[1]), z[2]);
                float m2 = fmaxf(fmaxf(z[3], z[4]), z[5]);
                float m3 = fmaxf(fmaxf(z[6], z[7]), z[8]);
                acc[ff] += fmaxf(fmaxf(m1, m2), m3);
            }
        }
    }

    // out[b, r, i, j, f] ; each lane writes its 16 contiguous f's
    float* op = out + ((((b * 4 + r) * H_ + i) * W_ + j) * F_ + half * 16);
    #pragma unroll
    for (int s = 0; s < 4; s++) {
        reinterpret_cast<float4*>(op)[s] =
            make_float4(acc[s * 4 + 0], acc[s * 4 + 1], acc[s * 4 + 2], acc[s * 4 + 3]);
    }
}

extern "C" void kernel_launch(void* const* d_in, const int* in_sizes, int n_in,
                              void* d_out, int out_size, void* d_ws, size_t ws_size,
                              hipStream_t stream) {
    const float* x    = (const float*)d_in[0];
    const float* kern = (const float*)d_in[1];
    const float* tker = (const float*)d_in[2];
    float* out = (float*)d_out;

    hipLaunchKernelGGL(mtp_prep, dim3(8), dim3(256), 0, stream, kern, tker);
    hipLaunchKernelGGL(mtp_main, dim3(512), dim3(256), 0, stream, x, out);
}

// Round 2
// 75.117 us; speedup vs baseline: 1.0680x; 1.0680x over previous
//
#include <hip/hip_runtime.h>

// Problem constants (from reference setup_inputs)
#define B_  4
#define H_  64
#define W_  64
#define C_  16
#define F_  32
#define PH  66   // padded height (+1 each side)
#define PW  66   // padded width

// Padded input image, zero borders: [B][PH][PW][C]  (~1.1 MB, rewritten each call)
__device__ float g_xpad[B_ * PH * PW * C_];

// Rotated/repacked weights: [r][cc(8)][pt(18)][f(32)][c2(2)] float2 entries
//   pt = p*2 + tk, tk: 0 = times (slope), 1 = plus (offset); cc = channel pair
__device__ float g_pack2[4 * 8 * 18 * F_ * 2];

// ---- prep A: rotate + repack weights ----
__global__ void mtp_prep_w(const float* __restrict__ kern, const float* __restrict__ tker) {
    int idx = blockIdx.x * 256 + threadIdx.x;        // over 4*8*18*32 = 18432
    if (idx >= 4 * 8 * 18 * F_) return;
    int f  = idx & 31;
    int t  = idx >> 5;
    int pt = t % 18;  t /= 18;
    int cc = t & 7;
    int r  = t >> 3;
    int p  = pt >> 1;
    int tk = pt & 1;
    int ki = p / 3, kj = p % 3;
    int si, sj;
    switch (r) {                                     // numpy rot90^r (CCW): out[ki,kj] = in[rot]
        case 0:  si = ki;      sj = kj;      break;
        case 1:  si = kj;      sj = 2 - ki;  break;
        case 2:  si = 2 - ki;  sj = 2 - kj;  break;
        default: si = 2 - kj;  sj = ki;      break;
    }
    const float* src = tk ? kern : tker;             // tk0 = times_kernel, tk1 = kernel
    float2 v;
    v.x = src[((si * 3 + sj) * C_ + cc * 2 + 0) * F_ + f];
    v.y = src[((si * 3 + sj) * C_ + cc * 2 + 1) * F_ + f];
    *reinterpret_cast<float2*>(g_pack2 + idx * 2) = v;
}

// ---- prep B: zero-pad x into g_xpad ----
__global__ void mtp_prep_x(const float* __restrict__ x) {
    int idx = blockIdx.x * 256 + threadIdx.x;        // over B*PH*PW*4 float4-chunks = 69696
    if (idx >= B_ * PH * PW * 4) return;
    int cc  = idx & 3;
    int t   = idx >> 2;
    int col = t % PW;  t /= PW;
    int row = t % PH;
    int b   = t / PH;
    float4 v = make_float4(0.f, 0.f, 0.f, 0.f);
    if (row >= 1 && row <= H_ && col >= 1 && col <= W_)
        v = *reinterpret_cast<const float4*>(
                x + ((b * H_ + row - 1) * W_ + col - 1) * C_ + cc * 4);
    *reinterpret_cast<float4*>(g_xpad + idx * 4) = v;
}

// ---- main: wave = (b, r, row i, 16-pixel strip). lane = (pixel parity, f). ----
// Weights held in VGPRs per channel-pair, reused across all 16 pixels.
__global__ __launch_bounds__(256) void mtp_main(float* __restrict__ out) {
    const int lane = threadIdx.x & 63;
    const int f    = lane & 31;                      // output feature
    const int ps   = lane >> 5;                      // pixel slot (0/1)
    const int wid  = (blockIdx.x << 2) + (threadIdx.x >> 6);   // 0..4095
    const int jq   = wid & 3;                        // 16-pixel strip
    const int i    = (wid >> 2) & 63;                // row
    const int r    = (wid >> 8) & 3;                 // rotation
    const int b    = wid >> 10;                      // batch
    const int jb   = jq << 4;

    // padded row pointers: original row i+di-1 -> padded row i+di; col jb+ps+dj-1+it*2 -> padded jb+ps+dj+it*2
    const float* rp0 = g_xpad + ((b * PH + i) * PW + jb + ps) * C_;
    const float* rp1 = rp0 + PW * C_;
    const float* rp2 = rp0 + 2 * PW * C_;

    float acc[8];
    #pragma unroll
    for (int it = 0; it < 8; ++it) acc[it] = 0.f;

    #pragma unroll 1
    for (int cc = 0; cc < 8; ++cc) {                 // channel pairs
        // weights for this (r, cc) and this lane's f: 9 positions x {times, plus}
        float2 wt[9], wk[9];
        const float* wb = g_pack2 + (((r * 8 + cc) * 18) * F_ + f) * 2;
        #pragma unroll
        for (int p = 0; p < 9; ++p) {
            wt[p] = *reinterpret_cast<const float2*>(wb + (p * 2 + 0) * F_ * 2);
            wk[p] = *reinterpret_cast<const float2*>(wb + (p * 2 + 1) * F_ * 2);
        }
        #pragma unroll
        for (int it = 0; it < 8; ++it) {             // pixel pairs along the strip
            float2 xv[9];
            #pragma unroll
            for (int dj = 0; dj < 3; ++dj) {
                xv[0 * 3 + dj] = *reinterpret_cast<const float2*>(rp0 + (it * 2 + dj) * C_ + cc * 2);
                xv[1 * 3 + dj] = *reinterpret_cast<const float2*>(rp1 + (it * 2 + dj) * C_ + cc * 2);
                xv[2 * 3 + dj] = *reinterpret_cast<const float2*>(rp2 + (it * 2 + dj) * C_ + cc * 2);
            }
            float z0[9], z1[9];
            #pragma unroll
            for (int p = 0; p < 9; ++p) {
                z0[p] = fmaf(xv[p].x, wt[p].x, wk[p].x);
                z1[p] = fmaf(xv[p].y, wt[p].y, wk[p].y);
            }
            // 9-way max as max3 trees
            float m0 = fmaxf(fmaxf(fmaxf(z0[0], z0[1]), z0[2]),
                       fmaxf(fmaxf(fmaxf(z0[3], z0[4]), z0[5]),
                             fmaxf(fmaxf(z0[6], z0[7]), z0[8])));
            float m1 = fmaxf(fmaxf(fmaxf(z1[0], z1[1]), z1[2]),
                       fmaxf(fmaxf(fmaxf(z1[3], z1[4]), z1[5]),
                             fmaxf(fmaxf(z1[6], z1[7]), z1[8])));
            acc[it] += m0 + m1;
        }
    }

    // out[b, r, i, jb+ps+it*2, f]; lanes of a wave cover 2 pixels x 32 f = 256B/store
    float* op = out + ((((b * 4 + r) * H_ + i) * W_ + jb + ps) * F_ + f);
    #pragma unroll
    for (int it = 0; it < 8; ++it)
        op[it * 2 * F_] = acc[it];
}

extern "C" void kernel_launch(void* const* d_in, const int* in_sizes, int n_in,
                              void* d_out, int out_size, void* d_ws, size_t ws_size,
                              hipStream_t stream) {
    const float* x    = (const float*)d_in[0];
    const float* kern = (const float*)d_in[1];
    const float* tker = (const float*)d_in[2];
    float* out = (float*)d_out;

    hipLaunchKernelGGL(mtp_prep_w, dim3(72), dim3(256), 0, stream, kern, tker);
    hipLaunchKernelGGL(mtp_prep_x, dim3(273), dim3(256), 0, stream, x);
    hipLaunchKernelGGL(mtp_main, dim3(1024), dim3(256), 0, stream, out);
}

// Round 3
// 42.929 us; speedup vs baseline: 1.8688x; 1.7498x over previous
//
#include <hip/hip_runtime.h>

// Problem constants (from reference setup_inputs)
#define B_  4
#define H_  64
#define W_  64
#define C_  16
#define F_  32
#define PH  66   // padded height
#define PW  66   // padded width

// Padded input, zero borders: [B][PH][PW][C]  (~1.1 MB)
__device__ float g_xpad[B_ * PH * PW * C_];
// Base-orientation weights (P4 handled by patch permutation, not weight rotation):
// layout [cc(8)][tk(2)][p(9)][f(32)][c2(2)]; tk0 = times (slope), tk1 = plus (offset)
__device__ float g_wpk[8 * 2 * 9 * F_ * 2];

#define NW (8 * 2 * 9 * F_)          // 4608 weight float2 entries
#define NX (B_ * PH * PW * 4)        // 69696 float4 pad chunks

// ---- prep: repack weights + zero-pad x (one launch) ----
__global__ void mtp_prep(const float* __restrict__ x,
                         const float* __restrict__ kern,
                         const float* __restrict__ tker) {
    int idx = blockIdx.x * 256 + threadIdx.x;
    if (idx < NW) {
        int f = idx & 31;
        int t = idx >> 5;            // 0..143
        int p = t % 9;  t /= 9;      // position (a*3+b), base orientation
        int tk = t & 1;
        int cc = t >> 1;             // channel pair
        const float* src = tk ? kern : tker;
        float2 v;
        v.x = src[(p * C_ + cc * 2 + 0) * F_ + f];
        v.y = src[(p * C_ + cc * 2 + 1) * F_ + f];
        *reinterpret_cast<float2*>(g_wpk + idx * 2) = v;
        return;
    }
    int xi = idx - NW;
    if (xi < NX) {
        int cc  = xi & 3;
        int t   = xi >> 2;
        int col = t % PW;  t /= PW;
        int row = t % PH;
        int b   = t / PH;
        float4 v = make_float4(0.f, 0.f, 0.f, 0.f);
        if (row >= 1 && row <= H_ && col >= 1 && col <= W_)
            v = *reinterpret_cast<const float4*>(
                    x + ((b * H_ + row - 1) * W_ + col - 1) * C_ + cc * 4);
        *reinterpret_cast<float4*>(g_xpad + xi * 4) = v;
    }
}

// 9-way max, grouped for v_max3 fusion
__device__ __forceinline__ float max9(const float* z) {
    float m1 = fmaxf(fmaxf(z[0], z[1]), z[2]);
    float m2 = fmaxf(fmaxf(z[3], z[4]), z[5]);
    float m3 = fmaxf(fmaxf(z[6], z[7]), z[8]);
    return fmaxf(fmaxf(m1, m2), m3);
}

// ---- main: wave = (b, i, 4-pixel strip), computes ALL 4 rotations ----
// lane = (pixel slot ps 0/1, f 0..31). 4096 waves = 1024 blocks x 4 waves.
// Per channel-pair: one 33-load batch (15 x-halo float2 + 18 weight float2),
// then 2 it x 4 r x 28 VALU of pure register compute.
__global__ __launch_bounds__(256) void mtp_main(float* __restrict__ out) {
    const int lane = threadIdx.x & 63;
    const int f    = lane & 31;
    const int ps   = lane >> 5;
    const int wid  = (blockIdx.x << 2) + (threadIdx.x >> 6);   // 0..4095
    const int jq   = wid & 15;                                 // 4-pixel strip
    const int i    = (wid >> 4) & 63;                          // row
    const int b    = wid >> 10;                                // batch
    const int jb   = jq << 2;

    // padded row pointers (orig row i+di-1 -> padded i+di; col jb+ps+lc-1 -> padded jb+ps+lc)
    const float* rp0 = g_xpad + ((b * PH + i) * PW + jb + ps) * C_;
    const float* rp1 = rp0 + PW * C_;
    const float* rp2 = rp0 + 2 * PW * C_;

    float acc[4][2];
    #pragma unroll
    for (int r = 0; r < 4; ++r) { acc[r][0] = 0.f; acc[r][1] = 0.f; }

    #pragma unroll 1
    for (int cc = 0; cc < 8; ++cc) {
        // weight batch: base orientation only (P4 via patch permutation)
        const float* wtb = g_wpk + ((cc * 2 + 0) * 9 * F_ + f) * 2;
        const float* wkb = g_wpk + ((cc * 2 + 1) * 9 * F_ + f) * 2;
        float2 wt[9], wk[9];
        #pragma unroll
        for (int p = 0; p < 9; ++p) {
            wt[p] = *reinterpret_cast<const float2*>(wtb + p * F_ * 2);
            wk[p] = *reinterpret_cast<const float2*>(wkb + p * F_ * 2);
        }
        // x halo batch: 3 rows x 5 local cols, serves both pixel-pairs
        float2 xh[3][5];
        #pragma unroll
        for (int lc = 0; lc < 5; ++lc) {
            xh[0][lc] = *reinterpret_cast<const float2*>(rp0 + lc * C_ + cc * 2);
            xh[1][lc] = *reinterpret_cast<const float2*>(rp1 + lc * C_ + cc * 2);
            xh[2][lc] = *reinterpret_cast<const float2*>(rp2 + lc * C_ + cc * 2);
        }
        #pragma unroll
        for (int it = 0; it < 2; ++it) {
            #pragma unroll
            for (int r = 0; r < 4; ++r) {
                float z0[9], z1[9];
                #pragma unroll
                for (int q = 0; q < 9; ++q) {
                    const int a = q / 3, bq = q % 3;
                    int di, dj;
                    switch (r) {   // x position = rot_r^{-1}(weight position q)
                        case 0:  di = a;      dj = bq;     break;
                        case 1:  di = 2 - bq; dj = a;      break;
                        case 2:  di = 2 - a;  dj = 2 - bq; break;
                        default: di = bq;     dj = 2 - a;  break;
                    }
                    const float2 xv = xh[di][it * 2 + dj];
                    z0[q] = fmaf(xv.x, wt[q].x, wk[q].x);
                    z1[q] = fmaf(xv.y, wt[q].y, wk[q].y);
                }
                acc[r][it] += max9(z0) + max9(z1);
            }
        }
    }

    // out[b, r, i, jb+ps+it*2, f]
    #pragma unroll
    for (int r = 0; r < 4; ++r) {
        float* op = out + ((((b * 4 + r) * H_ + i) * W_ + jb + ps) * F_ + f);
        op[0]      = acc[r][0];
        op[2 * F_] = acc[r][1];
    }
}

extern "C" void kernel_launch(void* const* d_in, const int* in_sizes, int n_in,
                              void* d_out, int out_size, void* d_ws, size_t ws_size,
                              hipStream_t stream) {
    const float* x    = (const float*)d_in[0];
    const float* kern = (const float*)d_in[1];
    const float* tker = (const float*)d_in[2];
    float* out = (float*)d_out;

    hipLaunchKernelGGL(mtp_prep, dim3((NW + NX + 255) / 256), dim3(256), 0, stream,
                       x, kern, tker);
    hipLaunchKernelGGL(mtp_main, dim3(1024), dim3(256), 0, stream, out);
}